// Round 8
// baseline (328.324 us; speedup 1.0000x reference)
//
#include <hip/hip_runtime.h>

typedef unsigned short u16;
typedef __attribute__((ext_vector_type(8))) __bf16 bf16x8;
typedef __attribute__((ext_vector_type(4))) float floatx4;

#define FLAG_F32OUT  1
#define FLAG_GELU    2
#define FLAG_PARTIAL 4
#define FLAG_PBF16   8

__device__ __forceinline__ u16 f2bf(float f) {
  union { float f; unsigned u; } un;
  un.f = f;
  unsigned u = un.u;
  u += 0x7fffu + ((u >> 16) & 1u);
  return (u16)(u >> 16);
}

__device__ __forceinline__ float bf2f(u16 h) {
  union { unsigned u; float f; } un;
  un.u = ((unsigned)h) << 16;
  return un.f;
}

__device__ __forceinline__ float gelu_f(float x) {
  float t = 1.5957691216f * (x + 0.044715f * x * x * x);
  return x / (1.0f + __expf(-t));
}

__device__ __forceinline__ floatx4 mfma16(bf16x8 a, bf16x8 b, floatx4 c) {
  return __builtin_amdgcn_mfma_f32_16x16x32_bf16(a, b, c, 0, 0, 0);
}

__device__ __forceinline__ void glds16(const void* g, void* l) {
  __builtin_amdgcn_global_load_lds(
      (__attribute__((address_space(1))) unsigned int*)(void*)g,
      (__attribute__((address_space(3))) unsigned int*)l, 16, 0, 0);
}

// ------- one-shot prep: weight transposes + qkv bias concat + LN1 ------------
// blocks 0..12287: 32x32 transpose tiles; 12288..12299: bias; 12300+: ln rows.
__global__ __launch_bounds__(256) void prep_all(
    const float* __restrict__ wq, const float* __restrict__ wk,
    const float* __restrict__ wv, const float* __restrict__ wo,
    const float* __restrict__ w1, const float* __restrict__ w2,
    const float* __restrict__ bq, const float* __restrict__ bk,
    const float* __restrict__ bv,
    u16* __restrict__ wqkvt, u16* __restrict__ wot,
    u16* __restrict__ w1t, u16* __restrict__ w2t,
    float* __restrict__ bqkv,
    const float* __restrict__ x, const float* __restrict__ ln1g,
    const float* __restrict__ ln1b, u16* __restrict__ h) {
  int b = blockIdx.x;
  int tx = threadIdx.x, ty = threadIdx.y;  // (32, 8)
  int tid = ty * 32 + tx;
  if (b >= 12300) {
    // -------- layernorm row --------
    int row = b - 12300;
    const float4* xr = (const float4*)(x + (size_t)row * 1024);
    float4 v = xr[tid];
    float s = v.x + v.y + v.z + v.w;
    float s2 = v.x * v.x + v.y * v.y + v.z * v.z + v.w * v.w;
#pragma unroll
    for (int m = 32; m >= 1; m >>= 1) {
      s += __shfl_xor(s, m, 64);
      s2 += __shfl_xor(s2, m, 64);
    }
    __shared__ float red[8];
    int wave = tid >> 6, lane = tid & 63;
    if (lane == 0) { red[wave] = s; red[4 + wave] = s2; }
    __syncthreads();
    s = red[0] + red[1] + red[2] + red[3];
    s2 = red[4] + red[5] + red[6] + red[7];
    float mu = s * (1.0f / 1024.0f);
    float var = s2 * (1.0f / 1024.0f) - mu * mu;
    float inv = rsqrtf(var + 1e-5f);
    float4 gv = ((const float4*)ln1g)[tid];
    float4 bv2 = ((const float4*)ln1b)[tid];
    ushort4 ov;
    ov.x = f2bf((v.x - mu) * inv * gv.x + bv2.x);
    ov.y = f2bf((v.y - mu) * inv * gv.y + bv2.y);
    ov.z = f2bf((v.z - mu) * inv * gv.z + bv2.z);
    ov.w = f2bf((v.w - mu) * inv * gv.w + bv2.w);
    *(ushort4*)(h + (size_t)row * 1024 + tid * 4) = ov;
    return;
  }
  if (b >= 12288) {
    int i = (b - 12288) * 256 + tid;
    float v = (i < 1024) ? bq[i] * 0.125f
                         : (i < 2048 ? bk[i - 1024] : bv[i - 2048]);
    bqkv[i] = v;
    return;
  }
  const float* W;
  u16* Wt;
  int K, N, bx, by;
  float scale = 1.0f;
  if (b < 4096) {
    int w = b >> 10, t = b & 1023;
    bx = t & 31; by = t >> 5; K = 1024; N = 1024;
    if (w == 0)      { W = wq; Wt = wqkvt;                scale = 0.125f; }
    else if (w == 1) { W = wk; Wt = wqkvt + 1024 * 1024; }
    else if (w == 2) { W = wv; Wt = wqkvt + 2 * 1024 * 1024; }
    else             { W = wo; Wt = wot; }
  } else if (b < 8192) {
    int t = b - 4096;
    bx = t & 127; by = t >> 7; K = 1024; N = 4096; W = w1; Wt = w1t;
  } else {
    int t = b - 8192;
    bx = t & 31; by = t >> 5; K = 4096; N = 1024; W = w2; Wt = w2t;
  }
  __shared__ float tile[32][33];
  int n0 = bx * 32, k0 = by * 32;
#pragma unroll
  for (int i = 0; i < 4; ++i)
    tile[ty + i * 8][tx] = W[(size_t)(k0 + ty + i * 8) * N + n0 + tx];
  __syncthreads();
#pragma unroll
  for (int i = 0; i < 4; ++i)
    Wt[(size_t)(n0 + ty + i * 8) * K + k0 + tx] =
        f2bf(tile[tx][ty + i * 8] * scale);
}

// ---------------- GEMM: C[M][N] = A[M][K](bf16) @ Bt[N][K]^T(bf16) + bias -----
// 128x128 tile, double-buffered BK=32 panels, ONE barrier per 32-K: the
// vmcnt(0) drain at each barrier covers loads issued a full compute phase ago.
// split-K via gridDim.z: z==0 -> outp; z>0 -> outp2 (+ (z-1)*M*N elements,
// bf16 when FLAG_PBF16 else fp32).
__global__ __launch_bounds__(256, 4) void gemm_bt(
    const u16* __restrict__ A, const u16* __restrict__ Bt,
    const float* __restrict__ bias,
    void* __restrict__ outp, void* __restrict__ outp2,
    int M, int N, int K, int Ks, int flags) {
  __shared__ __align__(16) u16 smem[17408];  // staging 32KB U C-tile 34816B
  u16* As = smem;          // buf0: 0..4095, buf1: 4096..8191
  u16* Bs = smem + 8192;   // buf0: 8192.., buf1: 12288..
  int tid = threadIdx.x;
  int lane = tid & 63, wave = tid >> 6;
  int lm = lane & 15, quad = lane >> 4;
  int wm = (wave >> 1) * 64, wn = (wave & 1) * 64;
  int bm = blockIdx.x, bn = blockIdx.y;
  int koff = blockIdx.z * Ks;

  const u16* aP = A + (size_t)(bm * 128 + (tid >> 2)) * K + koff + (tid & 3) * 8;
  const u16* bP = Bt + (size_t)(bn * 128 + (tid >> 2)) * K + koff + (tid & 3) * 8;
  u16* asD = As + tid * 8;
  u16* bsD = Bs + tid * 8;
  size_t rstep = (size_t)64 * K;

  floatx4 acc[4][4];
#pragma unroll
  for (int i = 0; i < 4; ++i)
#pragma unroll
    for (int j = 0; j < 4; ++j) acc[i][j] = (floatx4){0.f, 0.f, 0.f, 0.f};

  // prologue: stage k-panel 0 into buf0
  glds16(aP, asD);
  glds16(aP + rstep, asD + 2048);
  glds16(bP, bsD);
  glds16(bP + rstep, bsD + 2048);
  aP += 32;
  bP += 32;

  int nIter = Ks >> 5;  // always even (>=16) for our shapes
  for (int it = 0; it < nIter; it += 2) {
    // ---- even half: prefetch buf1, compute buf0 ----
    __syncthreads();  // buf0 loads drained; all waves done reading buf1
    glds16(aP, asD + 4096);
    glds16(aP + rstep, asD + 4096 + 2048);
    glds16(bP, bsD + 4096);
    glds16(bP + rstep, bsD + 4096 + 2048);
    aP += 32;
    bP += 32;
    {
      bf16x8 af[4], bfr[4];
#pragma unroll
      for (int mi = 0; mi < 4; ++mi)
        af[mi] = *(const bf16x8*)&As[(wm + mi * 16 + lm) * 32 + quad * 8];
#pragma unroll
      for (int ni = 0; ni < 4; ++ni)
        bfr[ni] = *(const bf16x8*)&Bs[(wn + ni * 16 + lm) * 32 + quad * 8];
#pragma unroll
      for (int mi = 0; mi < 4; ++mi)
#pragma unroll
        for (int ni = 0; ni < 4; ++ni)
          acc[mi][ni] = mfma16(af[mi], bfr[ni], acc[mi][ni]);
    }
    // ---- odd half: prefetch buf0, compute buf1 ----
    __syncthreads();  // buf1 loads drained; all waves done reading buf0
    if (it + 2 < nIter) {
      glds16(aP, asD);
      glds16(aP + rstep, asD + 2048);
      glds16(bP, bsD);
      glds16(bP + rstep, bsD + 2048);
      aP += 32;
      bP += 32;
    }
    {
      bf16x8 af[4], bfr[4];
#pragma unroll
      for (int mi = 0; mi < 4; ++mi)
        af[mi] = *(const bf16x8*)&As[4096 + (wm + mi * 16 + lm) * 32 + quad * 8];
#pragma unroll
      for (int ni = 0; ni < 4; ++ni)
        bfr[ni] = *(const bf16x8*)&Bs[4096 + (wn + ni * 16 + lm) * 32 + quad * 8];
#pragma unroll
      for (int mi = 0; mi < 4; ++mi)
#pragma unroll
        for (int ni = 0; ni < 4; ++ni)
          acc[mi][ni] = mfma16(af[mi], bfr[ni], acc[mi][ni]);
    }
  }

  bool gelu = (flags & FLAG_GELU) != 0;
  bool part = (flags & FLAG_PARTIAL) != 0;
  bool pbf = (flags & FLAG_PBF16) != 0;
  bool f32p = ((flags & FLAG_F32OUT) != 0) ||
              (part && !(pbf && blockIdx.z > 0));
  void* op;
  if (blockIdx.z == 0)
    op = outp;
  else
    op = (char*)outp2 +
         (size_t)(blockIdx.z - 1) * M * N * (pbf ? 2 : 4);

  if (!f32p) {
    u16* Ct = smem;
    __syncthreads();  // all waves done with staging LDS before C-tile reuse
#pragma unroll
    for (int ni = 0; ni < 4; ++ni) {
      int col = bn * 128 + wn + ni * 16 + lm;
      float bv = part ? 0.0f : bias[col];
#pragma unroll
      for (int mi = 0; mi < 4; ++mi) {
        int lr0 = wm + mi * 16 + quad * 4;
#pragma unroll
        for (int r = 0; r < 4; ++r) {
          float vv = acc[mi][ni][r] + bv;
          if (gelu) vv = gelu_f(vv);
          Ct[(lr0 + r) * 136 + wn + ni * 16 + lm] = f2bf(vv);
        }
      }
    }
    __syncthreads();
#pragma unroll
    for (int p = 0; p < 8; ++p) {
      int unit = p * 256 + tid;
      int row = unit >> 4, ch = unit & 15;
      uint4 v = *(const uint4*)&Ct[row * 136 + ch * 8];
      *(uint4*)&((u16*)op)[(size_t)(bm * 128 + row) * N + bn * 128 + ch * 8] = v;
    }
  } else {
    float* Cf = (float*)smem;
#pragma unroll
    for (int pp = 0; pp < 2; ++pp) {
      __syncthreads();
      if ((wave >> 1) == pp) {
#pragma unroll
        for (int ni = 0; ni < 4; ++ni) {
          int col = bn * 128 + wn + ni * 16 + lm;
          float bv = part ? 0.0f : bias[col];
#pragma unroll
          for (int mi = 0; mi < 4; ++mi) {
            int lr0 = mi * 16 + quad * 4;
#pragma unroll
            for (int r = 0; r < 4; ++r) {
              float vv = acc[mi][ni][r] + bv;
              if (gelu) vv = gelu_f(vv);
              Cf[(lr0 + r) * 132 + wn + ni * 16 + lm] = vv;
            }
          }
        }
      }
      __syncthreads();
#pragma unroll
      for (int p = 0; p < 8; ++p) {
        int unit = p * 256 + tid;
        int row = unit >> 5, ch = unit & 31;
        float4 v = *(const float4*)&Cf[row * 132 + ch * 4];
        size_t gi = (size_t)(bm * 128 + pp * 64 + row) * N + bn * 128 + ch * 4;
        *(float4*)&((float*)op)[gi] = v;
      }
    }
  }
}

// ---------------- flash attention over fused qkv [4096][3072] ----------------
__global__ __launch_bounds__(512) void flash_attn(
    const u16* __restrict__ qkv, u16* __restrict__ ctx) {
  __shared__ __align__(16) u16 Qs[128 * 72];
  __shared__ __align__(16) u16 Ks[64 * 72];
  __shared__ __align__(16) u16 Vt[64 * 64];    // XOR-swizzled

  int tid = threadIdx.x;
  int lane = tid & 63, wave = tid >> 6;  // 0..7
  int lm = lane & 15, quad = lane >> 4;
  int qt = blockIdx.x & 7;
  int hh = (blockIdx.x >> 3) & 15;
  int b = blockIdx.x >> 7;

  int krow = tid >> 3;        // 0..63
  int col8 = (tid & 7) * 8;
  int cb = col8 >> 3;

  size_t base_q = ((size_t)(b * 1024 + qt * 128)) * 3072 + hh * 64;
#pragma unroll
  for (int r = 0; r < 2; ++r) {
    int idx = r * 512 + tid;
    int row = idx >> 3;
    int c8 = (idx & 7) * 8;
    *(uint4*)&Qs[row * 72 + c8] =
        *(const uint4*)&qkv[base_q + (size_t)row * 3072 + c8];
  }
  __syncthreads();
  bf16x8 a0 = *(const bf16x8*)&Qs[(wave * 16 + lm) * 72 + quad * 8];
  bf16x8 a1 = *(const bf16x8*)&Qs[(wave * 16 + lm) * 72 + 32 + quad * 8];
  u16* Ps = &Qs[wave * 16 * 72];  // wave-private, aliases own Q rows

  float l_r[4];
  floatx4 acc[4];
#pragma unroll
  for (int r = 0; r < 4; ++r) l_r[r] = 0.0f;
#pragma unroll
  for (int d = 0; d < 4; ++d) acc[d] = (floatx4){0.f, 0.f, 0.f, 0.f};

  size_t kv0 = ((size_t)(b * 1024 + krow)) * 3072 + 1024 + hh * 64 + col8;
  const size_t kv_step = (size_t)64 * 3072;

  uint4 kreg = *(const uint4*)&qkv[kv0];
  uint4 vreg = *(const uint4*)&qkv[kv0 + 1024];

  int rw = krow >> 3;
  int rl = krow & 7;

  for (int j = 0; j < 16; ++j) {
    __syncthreads();
    *(uint4*)&Ks[krow * 72 + col8] = kreg;
    {
      u16* ve = (u16*)&vreg;
#pragma unroll
      for (int e = 0; e < 8; ++e) {
        int d = col8 + e;
        int chunk = (rw ^ cb ^ e) & 7;
        Vt[d * 64 + chunk * 8 + rl] = ve[e];
      }
    }
    __syncthreads();

    if (j < 15) {
      size_t kvn = kv0 + (size_t)(j + 1) * kv_step;
      kreg = *(const uint4*)&qkv[kvn];
      vreg = *(const uint4*)&qkv[kvn + 1024];
    }

    floatx4 sacc[4];
#pragma unroll
    for (int ni = 0; ni < 4; ++ni) {
      bf16x8 b0 = *(const bf16x8*)&Ks[(ni * 16 + lm) * 72 + quad * 8];
      bf16x8 b1 = *(const bf16x8*)&Ks[(ni * 16 + lm) * 72 + 32 + quad * 8];
      floatx4 z = (floatx4){0.f, 0.f, 0.f, 0.f};
      z = mfma16(a0, b0, z);
      z = mfma16(a1, b1, z);
      sacc[ni] = z;
    }

#pragma unroll
    for (int r = 0; r < 4; ++r) {
      float p0 = __expf(sacc[0][r]);
      float p1 = __expf(sacc[1][r]);
      float p2 = __expf(sacc[2][r]);
      float p3 = __expf(sacc[3][r]);
      l_r[r] += (p0 + p1) + (p2 + p3);
      Ps[(quad * 4 + r) * 72 + 0 * 16 + lm] = f2bf(p0);
      Ps[(quad * 4 + r) * 72 + 1 * 16 + lm] = f2bf(p1);
      Ps[(quad * 4 + r) * 72 + 2 * 16 + lm] = f2bf(p2);
      Ps[(quad * 4 + r) * 72 + 3 * 16 + lm] = f2bf(p3);
    }

    bf16x8 pa0 = *(const bf16x8*)&Ps[lm * 72 + quad * 8];
    bf16x8 pa1 = *(const bf16x8*)&Ps[lm * 72 + 32 + quad * 8];
#pragma unroll
    for (int dd = 0; dd < 4; ++dd) {
      int d = dd * 16 + lm;
      int dx = ((d >> 3) ^ d) & 7;
      bf16x8 vb0 = *(const bf16x8*)&Vt[d * 64 + ((quad ^ dx) & 7) * 8];
      bf16x8 vb1 = *(const bf16x8*)&Vt[d * 64 + (((4 + quad) ^ dx) & 7) * 8];
      acc[dd] = mfma16(pa0, vb0, acc[dd]);
      acc[dd] = mfma16(pa1, vb1, acc[dd]);
    }
  }

  float rl4[4];
#pragma unroll
  for (int r = 0; r < 4; ++r) {
    float sm = l_r[r];
#pragma unroll
    for (int mm = 1; mm < 16; mm <<= 1) sm += __shfl_xor(sm, mm, 64);
    rl4[r] = 1.0f / sm;
  }
#pragma unroll
  for (int dd = 0; dd < 4; ++dd)
#pragma unroll
    for (int r = 0; r < 4; ++r)
      Ps[(quad * 4 + r) * 72 + dd * 16 + lm] = f2bf(acc[dd][r] * rl4[r]);
  size_t obase = (size_t)(b * 1024 + qt * 128 + wave * 16);
#pragma unroll
  for (int p = 0; p < 2; ++p) {
    int unit = p * 64 + lane;
    int row = unit >> 3, ch = unit & 7;
    uint4 v = *(const uint4*)&Ps[row * 72 + ch * 8];
    *(uint4*)&ctx[(obase + row) * 1024 + hh * 64 + ch * 8] = v;
  }
}

// ------- fused: x2 = x2(p0) + p1 + x + bo;  h2 = LN(x2)*g + b (bf16) ---------
__global__ __launch_bounds__(256) void reduce_ln(
    float* __restrict__ x2, const float* __restrict__ p1,
    const float* __restrict__ x, const float* __restrict__ bo,
    const float* __restrict__ g, const float* __restrict__ bb,
    u16* __restrict__ h2) {
  int row = blockIdx.x, tid = threadIdx.x;
  size_t base = (size_t)row * 256;
  float4 a = ((const float4*)x2)[base + tid];
  float4 p = ((const float4*)p1)[base + tid];
  float4 c = ((const float4*)x)[base + tid];
  float4 d = ((const float4*)bo)[tid];
  float4 o;
  o.x = a.x + p.x + c.x + d.x;
  o.y = a.y + p.y + c.y + d.y;
  o.z = a.z + p.z + c.z + d.z;
  o.w = a.w + p.w + c.w + d.w;
  ((float4*)x2)[base + tid] = o;

  float s = o.x + o.y + o.z + o.w;
  float s2 = o.x * o.x + o.y * o.y + o.z * o.z + o.w * o.w;
#pragma unroll
  for (int m = 32; m >= 1; m >>= 1) {
    s += __shfl_xor(s, m, 64);
    s2 += __shfl_xor(s2, m, 64);
  }
  __shared__ float red[8];
  int wave = tid >> 6, lane = tid & 63;
  if (lane == 0) { red[wave] = s; red[4 + wave] = s2; }
  __syncthreads();
  s = red[0] + red[1] + red[2] + red[3];
  s2 = red[4] + red[5] + red[6] + red[7];
  float mu = s * (1.0f / 1024.0f);
  float var = s2 * (1.0f / 1024.0f) - mu * mu;
  float inv = rsqrtf(var + 1e-5f);
  float4 gv = ((const float4*)g)[tid];
  float4 bv = ((const float4*)bb)[tid];
  ushort4 ov;
  ov.x = f2bf((o.x - mu) * inv * gv.x + bv.x);
  ov.y = f2bf((o.y - mu) * inv * gv.y + bv.y);
  ov.z = f2bf((o.z - mu) * inv * gv.z + bv.z);
  ov.w = f2bf((o.w - mu) * inv * gv.w + bv.w);
  *(ushort4*)(h2 + (size_t)row * 1024 + tid * 4) = ov;
}

// ------- reduce: out = out(p0,f32) + 3x bf16 partials + resid + bias[1024] ---
__global__ __launch_bounds__(256) void reduce4b(
    float* __restrict__ out, const u16* __restrict__ pb,
    const float* __restrict__ resid, const float* __restrict__ bias) {
  int i = blockIdx.x * 256 + threadIdx.x;  // float4 index over 4096x1024
  float4 a = ((const float4*)out)[i];
  ushort4 q0 = ((const ushort4*)pb)[i];
  ushort4 q1 = ((const ushort4*)(pb + 4194304))[i];
  ushort4 q2 = ((const ushort4*)(pb + 8388608))[i];
  float4 c = ((const float4*)resid)[i];
  float4 d = ((const float4*)bias)[i & 255];
  float4 o;
  o.x = a.x + bf2f(q0.x) + bf2f(q1.x) + bf2f(q2.x) + c.x + d.x;
  o.y = a.y + bf2f(q0.y) + bf2f(q1.y) + bf2f(q2.y) + c.y + d.y;
  o.z = a.z + bf2f(q0.z) + bf2f(q1.z) + bf2f(q2.z) + c.z + d.z;
  o.w = a.w + bf2f(q0.w) + bf2f(q1.w) + bf2f(q2.w) + c.w + d.w;
  ((float4*)out)[i] = o;
}

extern "C" void kernel_launch(void* const* d_in, const int* in_sizes, int n_in,
                              void* d_out, int out_size, void* d_ws, size_t ws_size,
                              hipStream_t stream) {
  const float* x    = (const float*)d_in[0];
  const float* ln1g = (const float*)d_in[1];
  const float* ln1b = (const float*)d_in[2];
  const float* wq   = (const float*)d_in[3];
  const float* bq   = (const float*)d_in[4];
  const float* wk   = (const float*)d_in[5];
  const float* bk   = (const float*)d_in[6];
  const float* wv   = (const float*)d_in[7];
  const float* bv   = (const float*)d_in[8];
  const float* wo   = (const float*)d_in[9];
  const float* bo   = (const float*)d_in[10];
  const float* ln2g = (const float*)d_in[11];
  const float* ln2b = (const float*)d_in[12];
  const float* w1   = (const float*)d_in[13];
  const float* b1   = (const float*)d_in[14];
  const float* w2   = (const float*)d_in[15];
  const float* b2   = (const float*)d_in[16];

  char* ws = (char*)d_ws;
  const size_t MB = 1024ull * 1024ull;
  u16*   h     = (u16*)(ws + 0 * MB);    // 0-8: ln1 out -> later h2
  u16*   h2    = (u16*)(ws + 0 * MB);
  u16*   qkv   = (u16*)(ws + 8 * MB);    // 8-32 (dead after flash)
  float* pwo   = (float*)(ws + 8 * MB);  // 8-24: wo z=1 fp32 partial
  u16*   act   = (u16*)(ws + 8 * MB);    // 8-40: w1 out [4096][4096]
  u16*   ctxb  = (u16*)(ws + 32 * MB);   // 32-40
  float* bqkv  = (float*)(ws + 32 * MB); // aliased w/ ctxb (dead before flash)
  float* x2    = (float*)(ws + 40 * MB); // 40-56: fp32 residual stream
  u16*   pw2   = (u16*)(ws + 56 * MB);   // 56-80: w2 z=1..3 bf16 partials
  u16*   wqkvt = (u16*)(ws + 64 * MB);   // 64-70 (dead after qkv gemm)
  u16*   wot   = (u16*)(ws + 70 * MB);   // 70-72 (dead after wo gemm)
  u16*   w1t   = (u16*)(ws + 72 * MB);   // 72-80 (dead after w1 gemm)
  u16*   w2t   = (u16*)(ws + 80 * MB);   // 80-88 (live till w2)

  prep_all<<<16396, dim3(32, 8), 0, stream>>>(
      wq, wk, wv, wo, w1, w2, bq, bk, bv, wqkvt, wot, w1t, w2t, bqkv,
      x, ln1g, ln1b, h);

  // fused QKV: [4096][1024] @ [1024][3072] (wq/bq pre-scaled by 1/8)
  gemm_bt<<<dim3(32, 24, 1), 256, 0, stream>>>(
      h, wqkvt, bqkv, (void*)qkv, nullptr, 4096, 3072, 1024, 1024, 0);

  flash_attn<<<512, 512, 0, stream>>>(qkv, ctxb);

  // wo: split-K=2, fp32 partials; residual+bias+LN2 fused in reduce_ln
  gemm_bt<<<dim3(32, 8, 2), 256, 0, stream>>>(
      ctxb, wot, nullptr, (void*)x2, (void*)pwo, 4096, 1024, 1024, 512,
      FLAG_PARTIAL);
  reduce_ln<<<4096, 256, 0, stream>>>(x2, pwo, x, bo, ln2g, ln2b, h2);

  gemm_bt<<<dim3(32, 32, 1), 256, 0, stream>>>(
      h2, w1t, b1, (void*)act, nullptr, 4096, 4096, 1024, 1024, FLAG_GELU);

  // w2: split-K=4 -> z0 fp32 partial in d_out, z1..3 bf16 partials in pw2
  gemm_bt<<<dim3(32, 8, 4), 256, 0, stream>>>(
      act, w2t, nullptr, d_out, (void*)pw2, 4096, 1024, 4096, 1024,
      FLAG_PARTIAL | FLAG_PBF16);
  reduce4b<<<4096, 256, 0, stream>>>((float*)d_out, pw2, x2, b2);
}

// Round 9
// 326.606 us; speedup vs baseline: 1.0053x; 1.0053x over previous
//
#include <hip/hip_runtime.h>

typedef unsigned short u16;
typedef __attribute__((ext_vector_type(8))) __bf16 bf16x8;
typedef __attribute__((ext_vector_type(4))) float floatx4;

#define FLAG_F32OUT  1
#define FLAG_GELU    2
#define FLAG_PARTIAL 4
#define FLAG_PBF16   8

__device__ __forceinline__ u16 f2bf(float f) {
  union { float f; unsigned u; } un;
  un.f = f;
  unsigned u = un.u;
  u += 0x7fffu + ((u >> 16) & 1u);
  return (u16)(u >> 16);
}

__device__ __forceinline__ float bf2f(u16 h) {
  union { unsigned u; float f; } un;
  un.u = ((unsigned)h) << 16;
  return un.f;
}

__device__ __forceinline__ float gelu_f(float x) {
  float t = 1.5957691216f * (x + 0.044715f * x * x * x);
  return x / (1.0f + __expf(-t));
}

__device__ __forceinline__ floatx4 mfma16(bf16x8 a, bf16x8 b, floatx4 c) {
  return __builtin_amdgcn_mfma_f32_16x16x32_bf16(a, b, c, 0, 0, 0);
}

// ------- one-shot prep: weight transposes + qkv bias concat + LN1 ------------
// blocks 0..12287: 32x32 transpose tiles; 12288..12299: bias; 12300+: ln rows.
__global__ __launch_bounds__(256) void prep_all(
    const float* __restrict__ wq, const float* __restrict__ wk,
    const float* __restrict__ wv, const float* __restrict__ wo,
    const float* __restrict__ w1, const float* __restrict__ w2,
    const float* __restrict__ bq, const float* __restrict__ bk,
    const float* __restrict__ bv,
    u16* __restrict__ wqkvt, u16* __restrict__ wot,
    u16* __restrict__ w1t, u16* __restrict__ w2t,
    float* __restrict__ bqkv,
    const float* __restrict__ x, const float* __restrict__ ln1g,
    const float* __restrict__ ln1b, u16* __restrict__ h) {
  int b = blockIdx.x;
  int tx = threadIdx.x, ty = threadIdx.y;  // (32, 8)
  int tid = ty * 32 + tx;
  if (b >= 12300) {
    // -------- layernorm row --------
    int row = b - 12300;
    const float4* xr = (const float4*)(x + (size_t)row * 1024);
    float4 v = xr[tid];
    float s = v.x + v.y + v.z + v.w;
    float s2 = v.x * v.x + v.y * v.y + v.z * v.z + v.w * v.w;
#pragma unroll
    for (int m = 32; m >= 1; m >>= 1) {
      s += __shfl_xor(s, m, 64);
      s2 += __shfl_xor(s2, m, 64);
    }
    __shared__ float red[8];
    int wave = tid >> 6, lane = tid & 63;
    if (lane == 0) { red[wave] = s; red[4 + wave] = s2; }
    __syncthreads();
    s = red[0] + red[1] + red[2] + red[3];
    s2 = red[4] + red[5] + red[6] + red[7];
    float mu = s * (1.0f / 1024.0f);
    float var = s2 * (1.0f / 1024.0f) - mu * mu;
    float inv = rsqrtf(var + 1e-5f);
    float4 gv = ((const float4*)ln1g)[tid];
    float4 bv2 = ((const float4*)ln1b)[tid];
    ushort4 ov;
    ov.x = f2bf((v.x - mu) * inv * gv.x + bv2.x);
    ov.y = f2bf((v.y - mu) * inv * gv.y + bv2.y);
    ov.z = f2bf((v.z - mu) * inv * gv.z + bv2.z);
    ov.w = f2bf((v.w - mu) * inv * gv.w + bv2.w);
    *(ushort4*)(h + (size_t)row * 1024 + tid * 4) = ov;
    return;
  }
  if (b >= 12288) {
    int i = (b - 12288) * 256 + tid;
    float v = (i < 1024) ? bq[i] * 0.125f
                         : (i < 2048 ? bk[i - 1024] : bv[i - 2048]);
    bqkv[i] = v;
    return;
  }
  const float* W;
  u16* Wt;
  int K, N, bx, by;
  float scale = 1.0f;
  if (b < 4096) {
    int w = b >> 10, t = b & 1023;
    bx = t & 31; by = t >> 5; K = 1024; N = 1024;
    if (w == 0)      { W = wq; Wt = wqkvt;                scale = 0.125f; }
    else if (w == 1) { W = wk; Wt = wqkvt + 1024 * 1024; }
    else if (w == 2) { W = wv; Wt = wqkvt + 2 * 1024 * 1024; }
    else             { W = wo; Wt = wot; }
  } else if (b < 8192) {
    int t = b - 4096;
    bx = t & 127; by = t >> 7; K = 1024; N = 4096; W = w1; Wt = w1t;
  } else {
    int t = b - 8192;
    bx = t & 31; by = t >> 5; K = 4096; N = 1024; W = w2; Wt = w2t;
  }
  __shared__ float tile[32][33];
  int n0 = bx * 32, k0 = by * 32;
#pragma unroll
  for (int i = 0; i < 4; ++i)
    tile[ty + i * 8][tx] = W[(size_t)(k0 + ty + i * 8) * N + n0 + tx];
  __syncthreads();
#pragma unroll
  for (int i = 0; i < 4; ++i)
    Wt[(size_t)(n0 + ty + i * 8) * K + k0 + tx] =
        f2bf(tile[tx][ty + i * 8] * scale);
}

// ---------------- GEMM: C[M][N] = A[M][K](bf16) @ Bt[N][K]^T(bf16) + bias -----
// 128x128 tile, BK=64 (two 32-K panels), register-staged pipeline:
// next panel's A/B loaded to VGPRs during current compute (full-iteration
// latency cover), ds_write'd into the single staging buffer after the
// compute-done barrier. Neither barrier drains fresh vmem.
// split-K via gridDim.z: z==0 -> outp; z>0 -> outp2 (+ (z-1)*M*N elements,
// bf16 when FLAG_PBF16 else fp32).
__global__ __launch_bounds__(256, 4) void gemm_bt(
    const u16* __restrict__ A, const u16* __restrict__ Bt,
    const float* __restrict__ bias,
    void* __restrict__ outp, void* __restrict__ outp2,
    int M, int N, int K, int Ks, int flags) {
  __shared__ __align__(16) u16 smem[17408];  // staging 32KB U C-tile 34816B
  u16* As = smem;          // panels at 0, 4096 (u16), [128][32] each
  u16* Bs = smem + 8192;   // panels at 8192, 12288
  int tid = threadIdx.x;
  int lane = tid & 63, wave = tid >> 6;
  int lm = lane & 15, quad = lane >> 4;
  int wm = (wave >> 1) * 64, wn = (wave & 1) * 64;
  int bm = blockIdx.x, bn = blockIdx.y;
  int koff = blockIdx.z * Ks;

  const u16* aP = A + (size_t)(bm * 128 + (tid >> 2)) * K + koff + (tid & 3) * 8;
  const u16* bP = Bt + (size_t)(bn * 128 + (tid >> 2)) * K + koff + (tid & 3) * 8;
  u16* asD = As + tid * 8;
  u16* bsD = Bs + tid * 8;
  size_t rstep = (size_t)64 * K;

  floatx4 acc[4][4];
#pragma unroll
  for (int i = 0; i < 4; ++i)
#pragma unroll
    for (int j = 0; j < 4; ++j) acc[i][j] = (floatx4){0.f, 0.f, 0.f, 0.f};

  // prologue: load k-panel pair 0 into registers
  uint4 ra0 = *(const uint4*)aP;
  uint4 ra1 = *(const uint4*)(aP + rstep);
  uint4 ra2 = *(const uint4*)(aP + 32);
  uint4 ra3 = *(const uint4*)(aP + 32 + rstep);
  uint4 rb0 = *(const uint4*)bP;
  uint4 rb1 = *(const uint4*)(bP + rstep);
  uint4 rb2 = *(const uint4*)(bP + 32);
  uint4 rb3 = *(const uint4*)(bP + 32 + rstep);
  aP += 64;
  bP += 64;

  int nIter = Ks >> 6;
  for (int it = 0; it < nIter; ++it) {
    __syncthreads();  // all waves done reading LDS from previous compute
    // commit registers -> LDS (vmcnt wait here covers loads issued one
    // full compute phase ago)
    *(uint4*)asD = ra0;
    *(uint4*)(asD + 2048) = ra1;
    *(uint4*)(asD + 4096) = ra2;
    *(uint4*)(asD + 4096 + 2048) = ra3;
    *(uint4*)bsD = rb0;
    *(uint4*)(bsD + 2048) = rb1;
    *(uint4*)(bsD + 4096) = rb2;
    *(uint4*)(bsD + 4096 + 2048) = rb3;
    // issue next iteration's loads now; they fly during this compute
    if (it + 1 < nIter) {
      ra0 = *(const uint4*)aP;
      ra1 = *(const uint4*)(aP + rstep);
      ra2 = *(const uint4*)(aP + 32);
      ra3 = *(const uint4*)(aP + 32 + rstep);
      rb0 = *(const uint4*)bP;
      rb1 = *(const uint4*)(bP + rstep);
      rb2 = *(const uint4*)(bP + 32);
      rb3 = *(const uint4*)(bP + 32 + rstep);
      aP += 64;
      bP += 64;
    }
    __syncthreads();  // LDS writes visible (lgkm-only, fast)
#pragma unroll
    for (int p = 0; p < 2; ++p) {
      bf16x8 af[4], bfr[4];
#pragma unroll
      for (int mi = 0; mi < 4; ++mi)
        af[mi] = *(const bf16x8*)&As[p * 4096 + (wm + mi * 16 + lm) * 32 + quad * 8];
#pragma unroll
      for (int ni = 0; ni < 4; ++ni)
        bfr[ni] = *(const bf16x8*)&Bs[p * 4096 + (wn + ni * 16 + lm) * 32 + quad * 8];
#pragma unroll
      for (int mi = 0; mi < 4; ++mi)
#pragma unroll
        for (int ni = 0; ni < 4; ++ni)
          acc[mi][ni] = mfma16(af[mi], bfr[ni], acc[mi][ni]);
    }
  }

  bool gelu = (flags & FLAG_GELU) != 0;
  bool part = (flags & FLAG_PARTIAL) != 0;
  bool pbf = (flags & FLAG_PBF16) != 0;
  bool f32p = ((flags & FLAG_F32OUT) != 0) ||
              (part && !(pbf && blockIdx.z > 0));
  void* op;
  if (blockIdx.z == 0)
    op = outp;
  else
    op = (char*)outp2 +
         (size_t)(blockIdx.z - 1) * M * N * (pbf ? 2 : 4);

  if (!f32p) {
    u16* Ct = smem;
    __syncthreads();  // all waves done with staging LDS before C-tile reuse
#pragma unroll
    for (int ni = 0; ni < 4; ++ni) {
      int col = bn * 128 + wn + ni * 16 + lm;
      float bv = part ? 0.0f : bias[col];
#pragma unroll
      for (int mi = 0; mi < 4; ++mi) {
        int lr0 = wm + mi * 16 + quad * 4;
#pragma unroll
        for (int r = 0; r < 4; ++r) {
          float vv = acc[mi][ni][r] + bv;
          if (gelu) vv = gelu_f(vv);
          Ct[(lr0 + r) * 136 + wn + ni * 16 + lm] = f2bf(vv);
        }
      }
    }
    __syncthreads();
#pragma unroll
    for (int p = 0; p < 8; ++p) {
      int unit = p * 256 + tid;
      int row = unit >> 4, ch = unit & 15;
      uint4 v = *(const uint4*)&Ct[row * 136 + ch * 8];
      *(uint4*)&((u16*)op)[(size_t)(bm * 128 + row) * N + bn * 128 + ch * 8] = v;
    }
  } else {
    float* Cf = (float*)smem;
#pragma unroll
    for (int pp = 0; pp < 2; ++pp) {
      __syncthreads();
      if ((wave >> 1) == pp) {
#pragma unroll
        for (int ni = 0; ni < 4; ++ni) {
          int col = bn * 128 + wn + ni * 16 + lm;
          float bv = part ? 0.0f : bias[col];
#pragma unroll
          for (int mi = 0; mi < 4; ++mi) {
            int lr0 = mi * 16 + quad * 4;
#pragma unroll
            for (int r = 0; r < 4; ++r) {
              float vv = acc[mi][ni][r] + bv;
              if (gelu) vv = gelu_f(vv);
              Cf[(lr0 + r) * 132 + wn + ni * 16 + lm] = vv;
            }
          }
        }
      }
      __syncthreads();
#pragma unroll
      for (int p = 0; p < 8; ++p) {
        int unit = p * 256 + tid;
        int row = unit >> 5, ch = unit & 31;
        float4 v = *(const float4*)&Cf[row * 132 + ch * 4];
        size_t gi = (size_t)(bm * 128 + pp * 64 + row) * N + bn * 128 + ch * 4;
        *(float4*)&((float*)op)[gi] = v;
      }
    }
  }
}

// ---------------- flash attention over fused qkv [4096][3072] ----------------
__global__ __launch_bounds__(512) void flash_attn(
    const u16* __restrict__ qkv, u16* __restrict__ ctx) {
  __shared__ __align__(16) u16 Qs[128 * 72];
  __shared__ __align__(16) u16 Ks[64 * 72];
  __shared__ __align__(16) u16 Vt[64 * 64];    // XOR-swizzled

  int tid = threadIdx.x;
  int lane = tid & 63, wave = tid >> 6;  // 0..7
  int lm = lane & 15, quad = lane >> 4;
  int qt = blockIdx.x & 7;
  int hh = (blockIdx.x >> 3) & 15;
  int b = blockIdx.x >> 7;

  int krow = tid >> 3;        // 0..63
  int col8 = (tid & 7) * 8;
  int cb = col8 >> 3;

  size_t base_q = ((size_t)(b * 1024 + qt * 128)) * 3072 + hh * 64;
#pragma unroll
  for (int r = 0; r < 2; ++r) {
    int idx = r * 512 + tid;
    int row = idx >> 3;
    int c8 = (idx & 7) * 8;
    *(uint4*)&Qs[row * 72 + c8] =
        *(const uint4*)&qkv[base_q + (size_t)row * 3072 + c8];
  }
  __syncthreads();
  bf16x8 a0 = *(const bf16x8*)&Qs[(wave * 16 + lm) * 72 + quad * 8];
  bf16x8 a1 = *(const bf16x8*)&Qs[(wave * 16 + lm) * 72 + 32 + quad * 8];
  u16* Ps = &Qs[wave * 16 * 72];  // wave-private, aliases own Q rows

  float l_r[4];
  floatx4 acc[4];
#pragma unroll
  for (int r = 0; r < 4; ++r) l_r[r] = 0.0f;
#pragma unroll
  for (int d = 0; d < 4; ++d) acc[d] = (floatx4){0.f, 0.f, 0.f, 0.f};

  size_t kv0 = ((size_t)(b * 1024 + krow)) * 3072 + 1024 + hh * 64 + col8;
  const size_t kv_step = (size_t)64 * 3072;

  uint4 kreg = *(const uint4*)&qkv[kv0];
  uint4 vreg = *(const uint4*)&qkv[kv0 + 1024];

  int rw = krow >> 3;
  int rl = krow & 7;

  for (int j = 0; j < 16; ++j) {
    __syncthreads();
    *(uint4*)&Ks[krow * 72 + col8] = kreg;
    {
      u16* ve = (u16*)&vreg;
#pragma unroll
      for (int e = 0; e < 8; ++e) {
        int d = col8 + e;
        int chunk = (rw ^ cb ^ e) & 7;
        Vt[d * 64 + chunk * 8 + rl] = ve[e];
      }
    }
    __syncthreads();

    if (j < 15) {
      size_t kvn = kv0 + (size_t)(j + 1) * kv_step;
      kreg = *(const uint4*)&qkv[kvn];
      vreg = *(const uint4*)&qkv[kvn + 1024];
    }

    floatx4 sacc[4];
#pragma unroll
    for (int ni = 0; ni < 4; ++ni) {
      bf16x8 b0 = *(const bf16x8*)&Ks[(ni * 16 + lm) * 72 + quad * 8];
      bf16x8 b1 = *(const bf16x8*)&Ks[(ni * 16 + lm) * 72 + 32 + quad * 8];
      floatx4 z = (floatx4){0.f, 0.f, 0.f, 0.f};
      z = mfma16(a0, b0, z);
      z = mfma16(a1, b1, z);
      sacc[ni] = z;
    }

#pragma unroll
    for (int r = 0; r < 4; ++r) {
      float p0 = __expf(sacc[0][r]);
      float p1 = __expf(sacc[1][r]);
      float p2 = __expf(sacc[2][r]);
      float p3 = __expf(sacc[3][r]);
      l_r[r] += (p0 + p1) + (p2 + p3);
      Ps[(quad * 4 + r) * 72 + 0 * 16 + lm] = f2bf(p0);
      Ps[(quad * 4 + r) * 72 + 1 * 16 + lm] = f2bf(p1);
      Ps[(quad * 4 + r) * 72 + 2 * 16 + lm] = f2bf(p2);
      Ps[(quad * 4 + r) * 72 + 3 * 16 + lm] = f2bf(p3);
    }

    bf16x8 pa0 = *(const bf16x8*)&Ps[lm * 72 + quad * 8];
    bf16x8 pa1 = *(const bf16x8*)&Ps[lm * 72 + 32 + quad * 8];
#pragma unroll
    for (int dd = 0; dd < 4; ++dd) {
      int d = dd * 16 + lm;
      int dx = ((d >> 3) ^ d) & 7;
      bf16x8 vb0 = *(const bf16x8*)&Vt[d * 64 + ((quad ^ dx) & 7) * 8];
      bf16x8 vb1 = *(const bf16x8*)&Vt[d * 64 + (((4 + quad) ^ dx) & 7) * 8];
      acc[dd] = mfma16(pa0, vb0, acc[dd]);
      acc[dd] = mfma16(pa1, vb1, acc[dd]);
    }
  }

  float rl4[4];
#pragma unroll
  for (int r = 0; r < 4; ++r) {
    float sm = l_r[r];
#pragma unroll
    for (int mm = 1; mm < 16; mm <<= 1) sm += __shfl_xor(sm, mm, 64);
    rl4[r] = 1.0f / sm;
  }
#pragma unroll
  for (int dd = 0; dd < 4; ++dd)
#pragma unroll
    for (int r = 0; r < 4; ++r)
      Ps[(quad * 4 + r) * 72 + dd * 16 + lm] = f2bf(acc[dd][r] * rl4[r]);
  size_t obase = (size_t)(b * 1024 + qt * 128 + wave * 16);
#pragma unroll
  for (int p = 0; p < 2; ++p) {
    int unit = p * 64 + lane;
    int row = unit >> 3, ch = unit & 7;
    uint4 v = *(const uint4*)&Ps[row * 72 + ch * 8];
    *(uint4*)&ctx[(obase + row) * 1024 + hh * 64 + ch * 8] = v;
  }
}

// ------- fused: x2 = x2(p0) + p1 + x + bo;  h2 = LN(x2)*g + b (bf16) ---------
__global__ __launch_bounds__(256) void reduce_ln(
    float* __restrict__ x2, const float* __restrict__ p1,
    const float* __restrict__ x, const float* __restrict__ bo,
    const float* __restrict__ g, const float* __restrict__ bb,
    u16* __restrict__ h2) {
  int row = blockIdx.x, tid = threadIdx.x;
  size_t base = (size_t)row * 256;
  float4 a = ((const float4*)x2)[base + tid];
  float4 p = ((const float4*)p1)[base + tid];
  float4 c = ((const float4*)x)[base + tid];
  float4 d = ((const float4*)bo)[tid];
  float4 o;
  o.x = a.x + p.x + c.x + d.x;
  o.y = a.y + p.y + c.y + d.y;
  o.z = a.z + p.z + c.z + d.z;
  o.w = a.w + p.w + c.w + d.w;
  ((float4*)x2)[base + tid] = o;

  float s = o.x + o.y + o.z + o.w;
  float s2 = o.x * o.x + o.y * o.y + o.z * o.z + o.w * o.w;
#pragma unroll
  for (int m = 32; m >= 1; m >>= 1) {
    s += __shfl_xor(s, m, 64);
    s2 += __shfl_xor(s2, m, 64);
  }
  __shared__ float red[8];
  int wave = tid >> 6, lane = tid & 63;
  if (lane == 0) { red[wave] = s; red[4 + wave] = s2; }
  __syncthreads();
  s = red[0] + red[1] + red[2] + red[3];
  s2 = red[4] + red[5] + red[6] + red[7];
  float mu = s * (1.0f / 1024.0f);
  float var = s2 * (1.0f / 1024.0f) - mu * mu;
  float inv = rsqrtf(var + 1e-5f);
  float4 gv = ((const float4*)g)[tid];
  float4 bv = ((const float4*)bb)[tid];
  ushort4 ov;
  ov.x = f2bf((o.x - mu) * inv * gv.x + bv.x);
  ov.y = f2bf((o.y - mu) * inv * gv.y + bv.y);
  ov.z = f2bf((o.z - mu) * inv * gv.z + bv.z);
  ov.w = f2bf((o.w - mu) * inv * gv.w + bv.w);
  *(ushort4*)(h2 + (size_t)row * 1024 + tid * 4) = ov;
}

// ------- reduce: out = out(p0,f32) + 3x bf16 partials + resid + bias[1024] ---
__global__ __launch_bounds__(256) void reduce4b(
    float* __restrict__ out, const u16* __restrict__ pb,
    const float* __restrict__ resid, const float* __restrict__ bias) {
  int i = blockIdx.x * 256 + threadIdx.x;  // float4 index over 4096x1024
  float4 a = ((const float4*)out)[i];
  ushort4 q0 = ((const ushort4*)pb)[i];
  ushort4 q1 = ((const ushort4*)(pb + 4194304))[i];
  ushort4 q2 = ((const ushort4*)(pb + 8388608))[i];
  float4 c = ((const float4*)resid)[i];
  float4 d = ((const float4*)bias)[i & 255];
  float4 o;
  o.x = a.x + bf2f(q0.x) + bf2f(q1.x) + bf2f(q2.x) + c.x + d.x;
  o.y = a.y + bf2f(q0.y) + bf2f(q1.y) + bf2f(q2.y) + c.y + d.y;
  o.z = a.z + bf2f(q0.z) + bf2f(q1.z) + bf2f(q2.z) + c.z + d.z;
  o.w = a.w + bf2f(q0.w) + bf2f(q1.w) + bf2f(q2.w) + c.w + d.w;
  ((float4*)out)[i] = o;
}

extern "C" void kernel_launch(void* const* d_in, const int* in_sizes, int n_in,
                              void* d_out, int out_size, void* d_ws, size_t ws_size,
                              hipStream_t stream) {
  const float* x    = (const float*)d_in[0];
  const float* ln1g = (const float*)d_in[1];
  const float* ln1b = (const float*)d_in[2];
  const float* wq   = (const float*)d_in[3];
  const float* bq   = (const float*)d_in[4];
  const float* wk   = (const float*)d_in[5];
  const float* bk   = (const float*)d_in[6];
  const float* wv   = (const float*)d_in[7];
  const float* bv   = (const float*)d_in[8];
  const float* wo   = (const float*)d_in[9];
  const float* bo   = (const float*)d_in[10];
  const float* ln2g = (const float*)d_in[11];
  const float* ln2b = (const float*)d_in[12];
  const float* w1   = (const float*)d_in[13];
  const float* b1   = (const float*)d_in[14];
  const float* w2   = (const float*)d_in[15];
  const float* b2   = (const float*)d_in[16];

  char* ws = (char*)d_ws;
  const size_t MB = 1024ull * 1024ull;
  u16*   h     = (u16*)(ws + 0 * MB);    // 0-8: ln1 out -> later h2
  u16*   h2    = (u16*)(ws + 0 * MB);
  u16*   qkv   = (u16*)(ws + 8 * MB);    // 8-32 (dead after flash)
  float* pwo   = (float*)(ws + 8 * MB);  // 8-24: wo z=1 fp32 partial
  u16*   act   = (u16*)(ws + 8 * MB);    // 8-40: w1 out [4096][4096]
  u16*   ctxb  = (u16*)(ws + 32 * MB);   // 32-40
  float* bqkv  = (float*)(ws + 32 * MB); // aliased w/ ctxb (dead before flash)
  float* x2    = (float*)(ws + 40 * MB); // 40-56: fp32 residual stream
  u16*   pw2   = (u16*)(ws + 56 * MB);   // 56-80: w2 z=1..3 bf16 partials
  u16*   wqkvt = (u16*)(ws + 64 * MB);   // 64-70 (dead after qkv gemm)
  u16*   wot   = (u16*)(ws + 70 * MB);   // 70-72 (dead after wo gemm)
  u16*   w1t   = (u16*)(ws + 72 * MB);   // 72-80 (dead after w1 gemm)
  u16*   w2t   = (u16*)(ws + 80 * MB);   // 80-88 (live till w2)

  prep_all<<<16396, dim3(32, 8), 0, stream>>>(
      wq, wk, wv, wo, w1, w2, bq, bk, bv, wqkvt, wot, w1t, w2t, bqkv,
      x, ln1g, ln1b, h);

  // fused QKV: [4096][1024] @ [1024][3072] (wq/bq pre-scaled by 1/8)
  gemm_bt<<<dim3(32, 24, 1), 256, 0, stream>>>(
      h, wqkvt, bqkv, (void*)qkv, nullptr, 4096, 3072, 1024, 1024, 0);

  flash_attn<<<512, 512, 0, stream>>>(qkv, ctxb);

  // wo: split-K=2, fp32 partials; residual+bias+LN2 fused in reduce_ln
  gemm_bt<<<dim3(32, 8, 2), 256, 0, stream>>>(
      ctxb, wot, nullptr, (void*)x2, (void*)pwo, 4096, 1024, 1024, 512,
      FLAG_PARTIAL);
  reduce_ln<<<4096, 256, 0, stream>>>(x2, pwo, x, bo, ln2g, ln2b, h2);

  gemm_bt<<<dim3(32, 32, 1), 256, 0, stream>>>(
      h2, w1t, b1, (void*)act, nullptr, 4096, 4096, 1024, 1024, FLAG_GELU);

  // w2: split-K=4 -> z0 fp32 partial in d_out, z1..3 bf16 partials in pw2
  gemm_bt<<<dim3(32, 8, 4), 256, 0, stream>>>(
      act, w2t, nullptr, d_out, (void*)pw2, 4096, 1024, 4096, 1024,
      FLAG_PARTIAL | FLAG_PBF16);
  reduce4b<<<4096, 256, 0, stream>>>((float*)d_out, pw2, x2, b2);
}